// Round 2
// baseline (79.805 us; speedup 1.0000x reference)
//
#include <hip/hip_runtime.h>
#include <hip/hip_bf16.h>

#define B_ 8192
#define T_ 128
#define I_ 28
#define H_ 64
#define O_ 10
#define HS 72   // ushort stride per batch-row in h buffer (144 B, 16B-aligned)

typedef __attribute__((ext_vector_type(8))) short bf16x8;
typedef __attribute__((ext_vector_type(4))) float f32x4;

__device__ __forceinline__ unsigned short f2bf(float f) {
    unsigned int u = __builtin_bit_cast(unsigned int, f);
    u += 0x7fffu + ((u >> 16) & 1u);   // RNE
    return (unsigned short)(u >> 16);
}
__device__ __forceinline__ float bf2f(unsigned short h) {
    unsigned int u = ((unsigned int)h) << 16;
    return __builtin_bit_cast(float, u);
}
__device__ __forceinline__ float fast_tanh(float x) {
    float ax = fabsf(x);
    float t = __expf(-2.0f * ax);                       // e^{-2|x|}
    float r = (1.0f - t) * __builtin_amdgcn_rcpf(1.0f + t);
    return copysignf(r, x);
}

__launch_bounds__(256, 2)
__global__ void rnn_fused_kernel(const float* __restrict__ x,
                                 const float* __restrict__ W_ih,
                                 const float* __restrict__ W_hh,
                                 const float* __restrict__ b_ih,
                                 const float* __restrict__ b_hh,
                                 const float* __restrict__ W_out,
                                 const float* __restrict__ b_out,
                                 float* __restrict__ out) {
    __shared__ __align__(16) unsigned short h_lds[2][16 * HS];

    const int tid = threadIdx.x;
    const int lane = tid & 63;
    const int nt = tid >> 6;          // wave id == N-tile (h columns nt*16..+15)
    const int g = lane >> 4;          // k-group within fragment
    const int c = lane & 15;
    const int b0 = blockIdx.x * 16;   // batch tile base
    const int n = nt * 16 + c;        // output h column this lane owns

    // h0 = 0
    for (int i = tid; i < 16 * HS; i += 256) h_lds[0][i] = 0;

    // ---- per-wave constant B fragments, loaded once ----
    bf16x8 wih, whh0, whh1;
#pragma unroll
    for (int j = 0; j < 8; ++j) {
        int k = g * 8 + j;
        // B[k][n] = W^T[k][n] = W[n][k]; zero-pad k>=28 for the input proj
        wih[j]  = (k < I_) ? (short)f2bf(W_ih[n * I_ + k]) : (short)0;
        whh0[j] = (short)f2bf(W_hh[n * H_ + k]);
        whh1[j] = (short)f2bf(W_hh[n * H_ + 32 + k]);
    }
    const float bias = b_ih[n] + b_hh[n];
    const f32x4 biasC = {bias, bias, bias, bias};
    const f32x4 zeroC = {0.f, 0.f, 0.f, 0.f};

    // per-lane direct x A-fragment pointers: row = c, k = 8g..8g+7
    const float* xlo = x + (size_t)(b0 + c) * (T_ * I_) + g * 8;
    // g==3's upper half is k=28..31 (weight=0). Point it at valid memory so we
    // never load past the tensor end (garbage*0 is fine, OOB NaN bits are not).
    const float* xhi = (g < 3) ? (xlo + 4) : xlo;

    __syncthreads();   // h_lds[0] zeros visible; prefetch loads issued after

    float4 lo0, hi0, lo1, hi1, lo2, hi2, lo3, hi3;

#define LOADX(s, tt) do { int tc = ((tt) < T_) ? (tt) : (T_ - 1);            \
        lo##s = *reinterpret_cast<const float4*>(xlo + tc * I_);             \
        hi##s = *reinterpret_cast<const float4*>(xhi + tc * I_); } while (0)

#define XFRAG(s, dst) do {                                                   \
        dst[0] = (short)f2bf(lo##s.x); dst[1] = (short)f2bf(lo##s.y);        \
        dst[2] = (short)f2bf(lo##s.z); dst[3] = (short)f2bf(lo##s.w);        \
        dst[4] = (short)f2bf(hi##s.x); dst[5] = (short)f2bf(hi##s.y);        \
        dst[6] = (short)f2bf(hi##s.z); dst[7] = (short)f2bf(hi##s.w); } while (0)

    // 4-deep register prefetch pipeline
    LOADX(0, 0); LOADX(1, 1); LOADX(2, 2); LOADX(3, 3);

    // x-projection for t=0, hoisted out of the recurrence chain
    f32x4 px;
    {
        bf16x8 xf; XFRAG(0, xf);
        px = __builtin_amdgcn_mfma_f32_16x16x32_bf16(xf, wih, biasC, 0, 0, 0);
    }

    // Per sub-step (time t+u): read h[cur], issue prefetch for t+u+4 into
    // slot u, compute next step's x-projection from slot (u+1)&3, two parallel
    // recurrent MFMAs, tanh, write h[nxt]. Raw s_barrier with lgkmcnt-only
    // wait: global loads stay in flight across steps.
#define STEP(u, unext, CUR, NXT, TBASE) do {                                  \
        bf16x8 ah0 = *reinterpret_cast<const bf16x8*>(                        \
            &h_lds[CUR][c * HS + g * 8]);                                     \
        bf16x8 ah1 = *reinterpret_cast<const bf16x8*>(                        \
            &h_lds[CUR][c * HS + 32 + g * 8]);                                \
        LOADX(u, (TBASE) + (u) + 4);                                          \
        bf16x8 xf; XFRAG(unext, xf);                                          \
        f32x4 pxn = __builtin_amdgcn_mfma_f32_16x16x32_bf16(                  \
            xf, wih, biasC, 0, 0, 0);                                         \
        f32x4 a0 = __builtin_amdgcn_mfma_f32_16x16x32_bf16(                   \
            ah0, whh0, px, 0, 0, 0);                                          \
        f32x4 a1 = __builtin_amdgcn_mfma_f32_16x16x32_bf16(                   \
            ah1, whh1, zeroC, 0, 0, 0);                                       \
        _Pragma("unroll")                                                     \
        for (int r = 0; r < 4; ++r) {                                         \
            int m = g * 4 + r;                                                \
            h_lds[NXT][m * HS + n] = f2bf(fast_tanh(a0[r] + a1[r]));          \
        }                                                                     \
        px = pxn;                                                             \
        asm volatile("s_waitcnt lgkmcnt(0)" ::: "memory");                    \
        __builtin_amdgcn_s_barrier();                                         \
    } while (0)

    for (int t = 0; t < T_; t += 4) {
        STEP(0, 1, 0, 1, t);
        STEP(1, 2, 1, 0, t);
        STEP(2, 3, 0, 1, t);
        STEP(3, 0, 1, 0, t);
    }
#undef STEP
#undef XFRAG
#undef LOADX

    // epilogue: out[b][o] = h_last . W_out[o] + b_out[o]; final h is in buf 0
    if (tid < 160) {
        const int bl = tid & 15;
        const int o = tid >> 4;
        float s = b_out[o];
        const unsigned short* hrow = &h_lds[0][bl * HS];
#pragma unroll
        for (int k = 0; k < H_; ++k)
            s += bf2f(hrow[k]) * W_out[o * H_ + k];
        out[(size_t)(b0 + bl) * O_ + o] = s;
    }
}

extern "C" void kernel_launch(void* const* d_in, const int* in_sizes, int n_in,
                              void* d_out, int out_size, void* d_ws, size_t ws_size,
                              hipStream_t stream) {
    const float* x     = (const float*)d_in[0];
    const float* W_ih  = (const float*)d_in[1];
    const float* W_hh  = (const float*)d_in[2];
    const float* b_ih  = (const float*)d_in[3];
    const float* b_hh  = (const float*)d_in[4];
    const float* W_out = (const float*)d_in[5];
    const float* b_out = (const float*)d_in[6];
    float* out = (float*)d_out;

    dim3 grid(B_ / 16);
    dim3 block(256);
    rnn_fused_kernel<<<grid, block, 0, stream>>>(x, W_ih, W_hh, b_ih, b_hh,
                                                 W_out, b_out, out);
}